// Round 6
// baseline (713.448 us; speedup 1.0000x reference)
//
#include <hip/hip_runtime.h>
#include <stdint.h>

namespace {

typedef unsigned long long ull;
constexpr int B = 4, C = 128, H = 256, W = 256;
constexpr int V = H * W;              // 65536
constexpr int E = 163072;             // 32640+32512+32640+32512+32768
constexpr long long CHW = (long long)C * V;
constexpr int ROUNDS = 17;
constexpr int NBLK = (B * E) / 256;   // 2548 segment blocks

// Edge enumeration matches reference concat order: [L-vert, L-horiz, R-vert, R-horiz, cross]
__device__ __forceinline__ void edge_uv(int e, int& u, int& v) {
  if (e < 32640) {                       // L vertical
    int h = e >> 7, w = e & 127;
    u = (h << 8) + w; v = u + 256;
  } else if (e < 65152) {                // L horizontal
    int k = e - 32640; int h = k / 127, w = k - h * 127;
    u = (h << 8) + w; v = u + 1;
  } else if (e < 97792) {                // R vertical
    int k = e - 65152; int h = k >> 7, w = k & 127;
    u = (h << 8) + 128 + w; v = u + 256;
  } else if (e < 130304) {               // R horizontal
    int k = e - 97792; int h = k / 127, w = k - h * 127;
    u = (h << 8) + 128 + w; v = u + 1;
  } else {                               // cross
    int k = e - 130304; int h = k >> 7, w = k & 127;
    u = (h << 8) + w; v = u + 128;
  }
}

// Chase to effective root: self-loop, or min-id member of a 2-cycle
// (== reference cyc-break). Verified exact in R1-R5.
__device__ __forceinline__ int find_root(const int* __restrict__ par, int v) {
  int cur = v;
  for (int g = 0; g < 70000; ++g) {
    int p = par[cur];
    if (p == cur) break;
    int gp = par[p];
    if (gp == cur) { cur = cur < p ? cur : p; break; }
    cur = p;
  }
  return cur;
}

// Pass 1: per-pixel squared norm (fp64, same fma chain as verified) + init.
// cnt[1] = B*E (round 1 is a full scan), all other cnt slots 0.
__global__ void k_norm_init(const float* __restrict__ x, double* __restrict__ n2,
                            int* __restrict__ parent, ull* __restrict__ minE,
                            int* __restrict__ cnt) {
  int idx = blockIdx.x * blockDim.x + threadIdx.x;   // exact B*V grid
  int b = idx >> 16, p = idx & (V - 1);
  const float* xb = x + (long long)b * CHW + p;
  double acc = 0.0;
#pragma unroll 8
  for (int c = 0; c < C; ++c) {
    double t = (double)xb[(long long)c * V];
    acc = fma(t, t, acc);
  }
  n2[idx] = acc;
  parent[idx] = p;
  minE[idx] = ~0ULL;
  if (idx <= ROUNDS) cnt[idx] = (idx == 1) ? B * E : 0;
}

// Pass 2: pixel-PAIR threads, float2 loads, wave-uniform L/R (lanes 0-63 = L).
// Emits each edge exactly once with bit-identical math to the verified scalar
// version (ascending c, one fma per edge per c; same sqrt/div/round/pack).
// Fuses round-0's per-endpoint atomicMin (roots == endpoints at r0).
__global__ void k_weight2(const float* __restrict__ x, const double* __restrict__ n2,
                          ull* __restrict__ wkey, float* __restrict__ out,
                          ull* __restrict__ minE) {
  int idx = blockIdx.x * blockDim.x + threadIdx.x;   // exact B*H*128 grid
  int b = idx >> 15, rem = idx & 32767;
  int h = rem >> 7, q = rem & 127;
  int w0 = q << 1;
  bool isL  = q < 64;                                // wave-uniform
  bool hasV = h < 255;
  bool needR = isL ? (q < 63) : (q < 127);           // horiz edge at w0+1 exists
  int voff = hasV ? 256 : 0;                         // clamped (dummy) when absent
  int roff = needR ? 2 : 0;

  const float* xb = x + (long long)b * CHW + (h << 8) + w0;
  double dv0 = 0, dv1 = 0, dh0 = 0, dh1 = 0, dx0 = 0, dx1 = 0;
  if (isL) {
#pragma unroll 4
    for (int c = 0; c < C; ++c) {
      const float* pc = xb + (long long)c * V;
      float2 a  = *(const float2*)pc;
      float2 dn = *(const float2*)(pc + voff);
      float2 rt = *(const float2*)(pc + roff);
      float2 cr = *(const float2*)(pc + 128);
      dv0 = fma((double)a.x, (double)dn.x, dv0);
      dv1 = fma((double)a.y, (double)dn.y, dv1);
      dh0 = fma((double)a.x, (double)a.y, dh0);
      dh1 = fma((double)a.y, (double)rt.x, dh1);
      dx0 = fma((double)a.x, (double)cr.x, dx0);
      dx1 = fma((double)a.y, (double)cr.y, dx1);
    }
  } else {
#pragma unroll 4
    for (int c = 0; c < C; ++c) {
      const float* pc = xb + (long long)c * V;
      float2 a  = *(const float2*)pc;
      float2 dn = *(const float2*)(pc + voff);
      float2 rt = *(const float2*)(pc + roff);
      dv0 = fma((double)a.x, (double)dn.x, dv0);
      dv1 = fma((double)a.y, (double)dn.y, dv1);
      dh0 = fma((double)a.x, (double)a.y, dh0);
      dh1 = fma((double)a.y, (double)rt.x, dh1);
    }
  }

  const double* nb = n2 + (b << 16);
  ull* mb = minE + (b << 16);
  int p0 = (h << 8) + w0;
  auto emit = [&](int e, int u, int v, double dot) {
    double denom = fmax(sqrt(nb[u]) * sqrt(nb[v]), 1e-8);
    float wv = (float)(dot / denom);
    unsigned int bits = __float_as_uint(wv);
    if (wv == 0.0f) bits = 0u;                       // collapse -0.0
    unsigned int mapped = bits ^ (((int)bits < 0) ? 0xFFFFFFFFu : 0x80000000u);
    ull k = ((ull)mapped << 32) | (unsigned int)e;
    wkey[(size_t)b * E + e] = k;
    out[(size_t)b * E + e] = 0.0f;
    atomicMin(mb + u, k);                            // round-0 fused (fire-and-forget)
    atomicMin(mb + v, k);
  };
  if (isL) {
    if (hasV) {
      emit((h << 7) + w0,     p0,     p0 + 256, dv0);
      emit((h << 7) + w0 + 1, p0 + 1, p0 + 257, dv1);
    }
    emit(32640 + h * 127 + w0, p0, p0 + 1, dh0);
    if (q < 63) emit(32640 + h * 127 + w0 + 1, p0 + 1, p0 + 2, dh1);
    emit(130304 + (h << 7) + w0,     p0,     p0 + 128, dx0);
    emit(130304 + (h << 7) + w0 + 1, p0 + 1, p0 + 129, dx1);
  } else {
    int wr = w0 - 128;
    if (hasV) {
      emit(65152 + (h << 7) + wr,     p0,     p0 + 256, dv0);
      emit(65152 + (h << 7) + wr + 1, p0 + 1, p0 + 257, dv1);
    }
    emit(97792 + h * 127 + wr, p0, p0 + 1, dh0);
    if (q < 127) emit(97792 + h * 127 + wr + 1, p0 + 1, p0 + 2, dh1);
  }
}

// Rounds 1..16 edge phase: per-block SEGMENT of the survivor list, compacted
// IN PLACE with ballot + LDS wave-prefix. No consumed atomics; one
// fire-and-forget atomicAdd per block (skip flags only).
__global__ void k_edgemin_seg(const int* __restrict__ parent, int* __restrict__ root,
                              const ull* __restrict__ wkey, ull* __restrict__ minE,
                              int* __restrict__ el, int* __restrict__ cntblk,
                              int* __restrict__ cnt, int r) {
  int j = blockIdx.x, t = threadIdx.x;
  if (r >= 2 && __hip_atomic_load(cnt + r, __ATOMIC_RELAXED,
                                  __HIP_MEMORY_SCOPE_AGENT) == 0)
    return;                                          // converged: uniform exit
  int base = j << 8;
  int cj = (r == 1) ? 256 : cntblk[j];               // r1 = full scan of own range

  bool sur = false;
  int idx = 0;
  if (t < cj) {                                      // read BEFORE the barrier
    idx = (r == 1) ? (base + t) : el[base + t];
    int b = idx / E, e = idx - b * E;
    int u, v; edge_uv(e, u, v);
    const int* par = parent + (b << 16);
    int ru = find_root(par, u);
    int rv = find_root(par, v);
    if (ru != rv) {
      sur = true;
      int* rt = root + (b << 16);
      rt[u] = ru;                                    // fresh roots for winner lookup
      rt[v] = rv;
      ull k = wkey[idx];
      ull* mb = minE + (b << 16);
      atomicMin(mb + ru, k);                         // fire-and-forget
      atomicMin(mb + rv, k);
    }
  }

  __shared__ int wcnt[4];
  ull msk = __ballot(sur);
  int lane = t & 63, wid = t >> 6;
  if (lane == 0) wcnt[wid] = (int)__popcll(msk);
  __syncthreads();                                   // all reads done above
  int woff = 0;
#pragma unroll
  for (int k2 = 0; k2 < 4; ++k2)
    if (k2 < wid) woff += wcnt[k2];
  if (sur)
    el[base + woff + (int)__popcll(msk & ((1ULL << lane) - 1))] = idx;
  if (t == 0) {
    int surv = wcnt[0] + wcnt[1] + wcnt[2] + wcnt[3];
    cntblk[j] = surv;
    if (surv) atomicAdd(cnt + r + 1, surv);          // fire-and-forget
  }
}

// Vertex phase: chase own root, mark winner, hook, compress-on-change,
// re-arm dirtied minE slots. r==0 uses raw endpoints as roots (fused round).
__global__ void k_hook(ull* __restrict__ minE, const int* __restrict__ root,
                       int* __restrict__ parent, float* __restrict__ out,
                       const int* __restrict__ cnt, int r) {
  if (r >= 1 && __hip_atomic_load(cnt + r + 1, __ATOMIC_RELAXED,
                                  __HIP_MEMORY_SCOPE_AGENT) == 0)
    return;                                          // no cross edges this round
  int idx = blockIdx.x * blockDim.x + threadIdx.x;   // exact B*V grid
  int b = idx >> 16, v = idx & (V - 1);
  const int* par = parent + (b << 16);
  int old = par[v];
  int rr = find_root(par, v);
  int np = rr;                                       // compression (non-roots)
  if (rr == v) {
    ull k = minE[idx];
    if (k != ~0ULL) {
      int e = (int)(k & 0xFFFFFFFFu);
      int eu, ev; edge_uv(e, eu, ev);
      int ru, rv2;
      if (r == 0) { ru = eu; rv2 = ev; }             // roots == endpoints at r0
      else { const int* rt = root + (b << 16); ru = rt[eu]; rv2 = rt[ev]; }
      out[(size_t)b * E + e] = 1.0f;                 // winner (idempotent dup)
      np = (v == ru) ? rv2 : ru;                     // hook to other component
      minE[idx] = ~0ULL;                             // re-arm dirtied slot
    }
  }
  if (np != old) parent[idx] = np;
}

} // namespace

extern "C" void kernel_launch(void* const* d_in, const int* in_sizes, int n_in,
                              void* d_out, int out_size, void* d_ws, size_t ws_size,
                              hipStream_t stream) {
  const float* x = (const float*)d_in[0];
  float* out = (float*)d_out;

  char* ws = (char*)d_ws;
  size_t off = 0;
  auto alloc = [&](size_t bytes) {
    void* p = (void*)(ws + off);
    off += (bytes + 255) & ~(size_t)255;
    return p;
  };
  int* parent = (int*)alloc((size_t)B * V * sizeof(int));                      // 1 MB
  int* root   = (int*)alloc((size_t)B * V * sizeof(int));                      // 1 MB
  ull* minE   = (ull*)alloc((size_t)B * V * 8);                                // 2 MB
  double* n2  = (double*)alloc((size_t)B * V * sizeof(double));                // 2 MB
  ull* wkey   = (ull*)alloc((size_t)B * E * 8);                                // ~5 MB
  int* el     = (int*)alloc((size_t)B * E * sizeof(int));                      // ~2.6 MB
  int* cntblk = (int*)alloc((size_t)NBLK * sizeof(int));
  int* cnt    = (int*)alloc((ROUNDS + 1) * sizeof(int));

  k_norm_init<<<(B * V) / 256, 256, 0, stream>>>(x, n2, parent, minE, cnt);
  k_weight2<<<(B * H * 128) / 256, 256, 0, stream>>>(x, n2, wkey, out, minE);
  k_hook<<<(B * V) / 256, 256, 0, stream>>>(minE, root, parent, out, cnt, 0);

  for (int r = 1; r < ROUNDS; ++r) {
    k_edgemin_seg<<<NBLK, 256, 0, stream>>>(parent, root, wkey, minE,
                                            el, cntblk, cnt, r);
    k_hook<<<(B * V) / 256, 256, 0, stream>>>(minE, root, parent, out, cnt, r);
  }
}

// Round 7
// 495.788 us; speedup vs baseline: 1.4390x; 1.4390x over previous
//
#include <hip/hip_runtime.h>
#include <stdint.h>

namespace {

typedef unsigned long long ull;
constexpr int B = 4, C = 128, H = 256, W = 256;
constexpr int V = H * W;              // 65536
constexpr int E = 163072;             // 32640+32512+32640+32512+32768
constexpr long long CHW = (long long)C * V;
constexpr int ROUNDS = 17;

// Edge enumeration matches reference concat order: [L-vert, L-horiz, R-vert, R-horiz, cross]
__device__ __forceinline__ void edge_uv(int e, int& u, int& v) {
  if (e < 32640) {                       // L vertical
    int h = e >> 7, w = e & 127;
    u = (h << 8) + w; v = u + 256;
  } else if (e < 65152) {                // L horizontal
    int k = e - 32640; int h = k / 127, w = k - h * 127;
    u = (h << 8) + w; v = u + 1;
  } else if (e < 97792) {                // R vertical
    int k = e - 65152; int h = k >> 7, w = k & 127;
    u = (h << 8) + 128 + w; v = u + 256;
  } else if (e < 130304) {               // R horizontal
    int k = e - 97792; int h = k / 127, w = k - h * 127;
    u = (h << 8) + 128 + w; v = u + 1;
  } else {                               // cross
    int k = e - 130304; int h = k >> 7, w = k & 127;
    u = (h << 8) + w; v = u + 128;
  }
}

// Chase to effective root: self-loop, or min-id member of a 2-cycle
// (== reference cyc-break). Same semantics as the R1-R6 verified loop,
// rewritten to ONE dependent load per hop instead of two.
__device__ __forceinline__ int find_root(const int* __restrict__ par, int v) {
  int cur = v;
  int p = par[cur];
  for (int g = 0; g < 70000 && p != cur; ++g) {
    int gp = par[p];
    if (gp == cur) { cur = cur < p ? cur : p; break; }   // 2-cycle -> min id
    cur = p; p = gp;
  }
  return cur;
}

// Pass 1: per-pixel squared norm (fp64, verified fma chain) + flags init.
__global__ void k_norm_init(const float* __restrict__ x, double* __restrict__ n2,
                            int* __restrict__ flags) {
  int idx = blockIdx.x * blockDim.x + threadIdx.x;   // exact B*V grid
  int b = idx >> 16, p = idx & (V - 1);
  const float* xb = x + (long long)b * CHW + p;
  double acc = 0.0;
#pragma unroll 8
  for (int c = 0; c < C; ++c) {
    double t = (double)xb[(long long)c * V];
    acc = fma(t, t, acc);
  }
  n2[idx] = acc;
  if (idx < ROUNDS) flags[idx] = (idx == 0) ? 1 : 0; // r0 always merges
}

// Pass 2: per-edge cosine (fp64 dot), round once to fp32, pack sortable key.
// Bit-identical math to the R1/R3 version (verified exact). Also zeroes out.
__global__ void k_weight(const float* __restrict__ x, const double* __restrict__ n2,
                         ull* __restrict__ wkey, float* __restrict__ out) {
  int idx = blockIdx.x * blockDim.x + threadIdx.x;   // exact B*E grid
  int b = idx / E, e = idx - b * E;
  int u, v; edge_uv(e, u, v);
  const float* xb = x + (long long)b * CHW;
  double dot = 0.0;
#pragma unroll 8
  for (int c = 0; c < C; ++c) {
    long long off = (long long)c * V;
    dot = fma((double)xb[off + u], (double)xb[off + v], dot);
  }
  double denom = fmax(sqrt(n2[(b << 16) + u]) * sqrt(n2[(b << 16) + v]), 1e-8);
  float w = (float)(dot / denom);
  unsigned int bits = __float_as_uint(w);
  if (w == 0.0f) bits = 0u;                          // collapse -0.0
  unsigned int mapped = bits ^ (((int)bits < 0) ? 0xFFFFFFFFu : 0x80000000u);
  wkey[idx] = ((ull)mapped << 32) | (unsigned int)e;
  out[idx] = 0.0f;
}

// Round 0 vertex-min: roots are identities, so each vertex's component min is
// simply the min key over its incident edges. Direct store, NO atomics.
__global__ void k_vmin0(const ull* __restrict__ wkey, ull* __restrict__ minE) {
  int idx = blockIdx.x * blockDim.x + threadIdx.x;   // exact B*V grid
  int b = idx >> 16, v = idx & (V - 1);
  int h = v >> 8, w = v & 255;
  bool isL = w < 128;
  int wl = isL ? w : w - 128;
  int vb = isL ? 0 : 65152, hb = isL ? 32640 : 97792;
  const ull* wk = wkey + (size_t)b * E;
  ull m = ~0ULL;
  if (h > 0)    m = min(m, wk[vb + ((h - 1) << 7) + wl]);  // up
  if (h < 255)  m = min(m, wk[vb + (h << 7) + wl]);        // down
  if (wl > 0)   m = min(m, wk[hb + h * 127 + wl - 1]);     // left
  if (wl < 127) m = min(m, wk[hb + h * 127 + wl]);         // right
  m = min(m, wk[130304 + (h << 7) + wl]);                  // cross (always)
  minE[idx] = m;
}

// Round 0 hook: every vertex is a root; hook along its min edge, mark winner.
// (R6-verified r==0 path.) Re-arms minE for round 1.
__global__ void k_hook0(ull* __restrict__ minE, int* __restrict__ parent,
                        float* __restrict__ out) {
  int idx = blockIdx.x * blockDim.x + threadIdx.x;   // exact B*V grid
  int b = idx >> 16, v = idx & (V - 1);
  ull k = minE[idx];                                 // always a real key at r0
  int e = (int)(k & 0xFFFFFFFFu);
  int eu, ev; edge_uv(e, eu, ev);
  out[(size_t)b * E + e] = 1.0f;                     // winner (idempotent dup)
  parent[idx] = (v == eu) ? ev : eu;                 // hook to other endpoint
  minE[idx] = ~0ULL;                                 // re-arm
}

// Rounds 1..16 phase 1: per-vertex root snapshot (coalesced first hop).
__global__ void k_root(const int* __restrict__ parent, int* __restrict__ root,
                       const int* __restrict__ flags, int r) {
  if (__hip_atomic_load(flags + r - 1, __ATOMIC_RELAXED,
                        __HIP_MEMORY_SCOPE_AGENT) == 0)
    return;                                          // converged
  int idx = blockIdx.x * blockDim.x + threadIdx.x;   // exact B*V grid
  int b = idx >> 16;
  root[idx] = find_root(parent + (b << 16), idx & (V - 1));
}

// Rounds 1..16 phase 2: per-vertex min over incident cross-component edges.
// Neighbor roots are shifted coalesced streams; ONE atomicMin per vertex.
__global__ void k_vmin(const int* __restrict__ root, const ull* __restrict__ wkey,
                       ull* __restrict__ minE, int* __restrict__ flags, int r) {
  if (__hip_atomic_load(flags + r - 1, __ATOMIC_RELAXED,
                        __HIP_MEMORY_SCOPE_AGENT) == 0)
    return;                                          // converged
  int idx = blockIdx.x * blockDim.x + threadIdx.x;   // exact B*V grid
  int b = idx >> 16, v = idx & (V - 1);
  int h = v >> 8, w = v & 255;
  bool isL = w < 128;
  int wl = isL ? w : w - 128;
  int vb = isL ? 0 : 65152, hb = isL ? 32640 : 97792;
  const int* rt = root + (b << 16);
  const ull* wk = wkey + (size_t)b * E;
  int rme = rt[v];
  ull m = ~0ULL;
  if (h > 0    && rt[v - 256] != rme) m = min(m, wk[vb + ((h - 1) << 7) + wl]);
  if (h < 255  && rt[v + 256] != rme) m = min(m, wk[vb + (h << 7) + wl]);
  if (wl > 0   && rt[v - 1]   != rme) m = min(m, wk[hb + h * 127 + wl - 1]);
  if (wl < 127 && rt[v + 1]   != rme) m = min(m, wk[hb + h * 127 + wl]);
  int xn = isL ? v + 128 : v - 128;
  if (rt[xn] != rme) m = min(m, wk[130304 + (h << 7) + wl]);
  bool any = m != ~0ULL;
  if (any) atomicMin(minE + (b << 16) + rme, m);     // fire-and-forget
  ull msk = __ballot(any);
  if (msk && (threadIdx.x & 63) == 0 &&
      __hip_atomic_load(flags + r, __ATOMIC_RELAXED, __HIP_MEMORY_SCOPE_AGENT) == 0)
    __hip_atomic_fetch_or(flags + r, 1, __ATOMIC_RELAXED, __HIP_MEMORY_SCOPE_AGENT);
}

// Rounds 1..16 phase 3: winners + hook + compress (reads fresh root[], no chase).
__global__ void k_hook(ull* __restrict__ minE, const int* __restrict__ root,
                       int* __restrict__ parent, float* __restrict__ out,
                       const int* __restrict__ flags, int r) {
  if (__hip_atomic_load(flags + r, __ATOMIC_RELAXED,
                        __HIP_MEMORY_SCOPE_AGENT) == 0)
    return;                                          // no merges this round
  int idx = blockIdx.x * blockDim.x + threadIdx.x;   // exact B*V grid
  int b = idx >> 16, v = idx & (V - 1);
  int rr = root[idx];
  int np = rr;                                       // compression (non-roots)
  if (rr == v) {
    ull k = minE[idx];
    if (k != ~0ULL) {
      int e = (int)(k & 0xFFFFFFFFu);
      int eu, ev; edge_uv(e, eu, ev);
      const int* rt = root + (b << 16);
      int ru = rt[eu], rv2 = rt[ev];
      out[(size_t)b * E + e] = 1.0f;                 // winner (idempotent dup)
      np = (v == ru) ? rv2 : ru;                     // hook to other component
      minE[idx] = ~0ULL;                             // re-arm dirtied slot
    }
  }
  int* par = parent + (b << 16);
  if (par[v] != np) par[v] = np;
}

} // namespace

extern "C" void kernel_launch(void* const* d_in, const int* in_sizes, int n_in,
                              void* d_out, int out_size, void* d_ws, size_t ws_size,
                              hipStream_t stream) {
  const float* x = (const float*)d_in[0];
  float* out = (float*)d_out;

  char* ws = (char*)d_ws;
  size_t off = 0;
  auto alloc = [&](size_t bytes) {
    void* p = (void*)(ws + off);
    off += (bytes + 255) & ~(size_t)255;
    return p;
  };
  int* parent = (int*)alloc((size_t)B * V * sizeof(int));                      // 1 MB
  int* root   = (int*)alloc((size_t)B * V * sizeof(int));                      // 1 MB
  ull* minE   = (ull*)alloc((size_t)B * V * 8);                                // 2 MB
  double* n2  = (double*)alloc((size_t)B * V * sizeof(double));                // 2 MB
  ull* wkey   = (ull*)alloc((size_t)B * E * 8);                                // ~5 MB
  int* flags  = (int*)alloc(ROUNDS * sizeof(int));

  k_norm_init<<<(B * V) / 256, 256, 0, stream>>>(x, n2, flags);
  k_weight<<<(B * E) / 256, 256, 0, stream>>>(x, n2, wkey, out);
  k_vmin0<<<(B * V) / 256, 256, 0, stream>>>(wkey, minE);
  k_hook0<<<(B * V) / 256, 256, 0, stream>>>(minE, parent, out);

  for (int r = 1; r < ROUNDS; ++r) {
    k_root<<<(B * V) / 256, 256, 0, stream>>>(parent, root, flags, r);
    k_vmin<<<(B * V) / 256, 256, 0, stream>>>(root, wkey, minE, flags, r);
    k_hook<<<(B * V) / 256, 256, 0, stream>>>(minE, root, parent, out, flags, r);
  }
}

// Round 10
// 410.578 us; speedup vs baseline: 1.7377x; 1.2075x over previous
//
#include <hip/hip_runtime.h>
#include <stdint.h>

namespace {

typedef unsigned long long ull;
constexpr int B = 4, C = 128, H = 256, W = 256;
constexpr int V = H * W;              // 65536
constexpr int E = 163072;             // 32640+32512+32640+32512+32768
constexpr long long CHW = (long long)C * V;
constexpr int ROUNDS = 17;
constexpr int NBLKV = (B * V) / 256;  // 1024 vertex blocks
constexpr int SEG = 768;              // <=3 owned edges per vertex * 256

// Edge enumeration matches reference concat order: [L-vert, L-horiz, R-vert, R-horiz, cross]
__device__ __forceinline__ void edge_uv(int e, int& u, int& v) {
  if (e < 32640) {                       // L vertical
    int h = e >> 7, w = e & 127;
    u = (h << 8) + w; v = u + 256;
  } else if (e < 65152) {                // L horizontal
    int k = e - 32640; int h = k / 127, w = k - h * 127;
    u = (h << 8) + w; v = u + 1;
  } else if (e < 97792) {                // R vertical
    int k = e - 65152; int h = k >> 7, w = k & 127;
    u = (h << 8) + 128 + w; v = u + 256;
  } else if (e < 130304) {               // R horizontal
    int k = e - 97792; int h = k / 127, w = k - h * 127;
    u = (h << 8) + 128 + w; v = u + 1;
  } else {                               // cross
    int k = e - 130304; int h = k >> 7, w = k & 127;
    u = (h << 8) + w; v = u + 128;
  }
}

// Chase to effective root: self-loop, or min-id member of a 2-cycle
// (== reference cyc-break). Handles walking into a 2-cycle from outside.
// Verified exact R1-R7. MUST only run on a stable (non-mutating) parent.
__device__ __forceinline__ int find_root(const int* __restrict__ par, int v) {
  int cur = v;
  int p = par[cur];
  for (int g = 0; g < 70000 && p != cur; ++g) {
    int gp = par[p];
    if (gp == cur) { cur = cur < p ? cur : p; break; }   // 2-cycle -> min id
    cur = p; p = gp;
  }
  return cur;
}

// Pass 1: per-pixel squared norm (fp64, verified fma chain) + flags init.
__global__ void k_norm_init(const float* __restrict__ x, double* __restrict__ n2,
                            int* __restrict__ flags) {
  int idx = blockIdx.x * blockDim.x + threadIdx.x;   // exact B*V grid
  int b = idx >> 16, p = idx & (V - 1);
  const float* xb = x + (long long)b * CHW + p;
  double acc = 0.0;
#pragma unroll 8
  for (int c = 0; c < C; ++c) {
    double t = (double)xb[(long long)c * V];
    acc = fma(t, t, acc);
  }
  n2[idx] = acc;
  if (idx < ROUNDS) flags[idx] = (idx == 0) ? 1 : 0; // r0 always merges
}

// Pass 2: per-edge cosine (fp64 dot), verified bit-identical math. Zeroes out.
__global__ void k_weight(const float* __restrict__ x, const double* __restrict__ n2,
                         ull* __restrict__ wkey, float* __restrict__ out) {
  int idx = blockIdx.x * blockDim.x + threadIdx.x;   // exact B*E grid
  int b = idx / E, e = idx - b * E;
  int u, v; edge_uv(e, u, v);
  const float* xb = x + (long long)b * CHW;
  double dot = 0.0;
#pragma unroll 8
  for (int c = 0; c < C; ++c) {
    long long off = (long long)c * V;
    dot = fma((double)xb[off + u], (double)xb[off + v], dot);
  }
  double denom = fmax(sqrt(n2[(b << 16) + u]) * sqrt(n2[(b << 16) + v]), 1e-8);
  float w = (float)(dot / denom);
  unsigned int bits = __float_as_uint(w);
  if (w == 0.0f) bits = 0u;                          // collapse -0.0
  unsigned int mapped = bits ^ (((int)bits < 0) ? 0xFFFFFFFFu : 0x80000000u);
  wkey[idx] = ((ull)mapped << 32) | (unsigned int)e;
  out[idx] = 0.0f;
}

// Round 0 vertex-min: roots are identities. Direct store, NO atomics.
__global__ void k_vmin0(const ull* __restrict__ wkey, ull* __restrict__ minE) {
  int idx = blockIdx.x * blockDim.x + threadIdx.x;   // exact B*V grid
  int b = idx >> 16, v = idx & (V - 1);
  int h = v >> 8, w = v & 255;
  bool isL = w < 128;
  int wl = isL ? w : w - 128;
  int vb = isL ? 0 : 65152, hb = isL ? 32640 : 97792;
  const ull* wk = wkey + (size_t)b * E;
  ull m = ~0ULL;
  if (h > 0)    m = min(m, wk[vb + ((h - 1) << 7) + wl]);  // up
  if (h < 255)  m = min(m, wk[vb + (h << 7) + wl]);        // down
  if (wl > 0)   m = min(m, wk[hb + h * 127 + wl - 1]);     // left
  if (wl < 127) m = min(m, wk[hb + h * 127 + wl]);         // right
  m = min(m, wk[130304 + (h << 7) + wl]);                  // cross (both sides)
  minE[idx] = m;
}

// Round 0 hook: every vertex is a root; hook along its min edge, mark winner.
__global__ void k_hook0(ull* __restrict__ minE, int* __restrict__ parent,
                        float* __restrict__ out) {
  int idx = blockIdx.x * blockDim.x + threadIdx.x;   // exact B*V grid
  int b = idx >> 16, v = idx & (V - 1);
  ull k = minE[idx];                                 // always a real key at r0
  int e = (int)(k & 0xFFFFFFFFu);
  int eu, ev; edge_uv(e, eu, ev);
  out[(size_t)b * E + e] = 1.0f;                     // winner (idempotent dup)
  parent[idx] = (v == eu) ? ev : eu;                 // hook to other endpoint
  minE[idx] = ~0ULL;                                 // re-arm
}

// Round 1 phase 1: per-vertex root snapshot (coalesced first hop).
__global__ void k_root(const int* __restrict__ parent, int* __restrict__ root) {
  int idx = blockIdx.x * blockDim.x + threadIdx.x;   // exact B*V grid
  int b = idx >> 16;
  root[idx] = find_root(parent + (b << 16), idx & (V - 1));
}

// Round 1 phase 2: per-vertex min over ALL 5 incident cross edges (one
// atomicMin), PLUS append owned still-cross edges (down/right/cross-if-L)
// into this block's private el segment via LDS counter.
// R8/R9 BUG FIXED: right-half vertices must also consider their cross edge
// (owned by the left partner) as a min CANDIDATE.
__global__ void k_vmin1(const int* __restrict__ root, const ull* __restrict__ wkey,
                        ull* __restrict__ minE, int* __restrict__ flags,
                        int* __restrict__ el, int* __restrict__ cntblk) {
  __shared__ int lcnt;
  if (threadIdx.x == 0) lcnt = 0;
  __syncthreads();
  int idx = blockIdx.x * blockDim.x + threadIdx.x;   // exact B*V grid
  int b = idx >> 16, v = idx & (V - 1);
  int h = v >> 8, w = v & 255;
  bool isL = w < 128;
  int wl = isL ? w : w - 128;
  int vb = isL ? 0 : 65152, hb = isL ? 32640 : 97792;
  const int* rt = root + (b << 16);
  const ull* wk = wkey + (size_t)b * E;
  int rme = rt[v];
  ull m = ~0ULL;
  int base = blockIdx.x * SEG;
  // not owned: up / left / (cross for right half) -> min candidates only
  if (h > 0   && rt[v - 256] != rme) m = min(m, wk[vb + ((h - 1) << 7) + wl]);
  if (wl > 0  && rt[v - 1]   != rme) m = min(m, wk[hb + h * 127 + wl - 1]);
  if (!isL    && rt[v - 128] != rme) m = min(m, wk[130304 + (h << 7) + wl]);
  // owned: down / right / (cross for left half) -> min candidates + append
  if (h < 255 && rt[v + 256] != rme) {
    int e = vb + (h << 7) + wl;
    m = min(m, wk[e]);
    el[base + atomicAdd(&lcnt, 1)] = e;
  }
  if (wl < 127 && rt[v + 1] != rme) {
    int e = hb + h * 127 + wl;
    m = min(m, wk[e]);
    el[base + atomicAdd(&lcnt, 1)] = e;
  }
  if (isL && rt[v + 128] != rme) {
    int e = 130304 + (h << 7) + wl;
    m = min(m, wk[e]);
    el[base + atomicAdd(&lcnt, 1)] = e;
  }
  bool any = m != ~0ULL;
  if (any) atomicMin(minE + (b << 16) + rme, m);     // fire-and-forget
  ull msk = __ballot(any);
  if (msk && (threadIdx.x & 63) == 0 &&
      __hip_atomic_load(flags + 1, __ATOMIC_RELAXED, __HIP_MEMORY_SCOPE_AGENT) == 0)
    __hip_atomic_fetch_or(flags + 1, 1, __ATOMIC_RELAXED, __HIP_MEMORY_SCOPE_AGENT);
  __syncthreads();
  if (threadIdx.x == 0) cntblk[blockIdx.x] = lcnt;
}

// Round 1 phase 3: winners + hook + full path compression. Hook targets come
// from the root[] SNAPSHOT (stable) -> only mutual 2-cycles possible.
__global__ void k_hook1(ull* __restrict__ minE, const int* __restrict__ root,
                        int* __restrict__ parent, float* __restrict__ out,
                        const int* __restrict__ flags) {
  if (__hip_atomic_load(flags + 1, __ATOMIC_RELAXED,
                        __HIP_MEMORY_SCOPE_AGENT) == 0)
    return;
  int idx = blockIdx.x * blockDim.x + threadIdx.x;   // exact B*V grid
  int b = idx >> 16, v = idx & (V - 1);
  int rr = root[idx];
  int np = rr;                                       // compression (non-roots)
  if (rr == v) {
    ull k = minE[idx];
    if (k != ~0ULL) {
      int e = (int)(k & 0xFFFFFFFFu);
      int eu, ev; edge_uv(e, eu, ev);
      const int* rt = root + (b << 16);
      int ru = rt[eu], rv2 = rt[ev];
      out[(size_t)b * E + e] = 1.0f;                 // winner (idempotent dup)
      np = (v == ru) ? rv2 : ru;                     // hook to other component
      minE[idx] = ~0ULL;                             // re-arm dirtied slot
    }
  }
  int* par = parent + (b << 16);
  if (par[v] != np) par[v] = np;
}

// Rounds 2..16 phase 1: per-block edge segment. Chase both roots on STABLE
// parent, atomicMin per component (fire-and-forget), in-place LDS
// re-compaction of survivors.
__global__ void k_edge(const int* __restrict__ parent, const ull* __restrict__ wkey,
                       ull* __restrict__ minE, int* __restrict__ el,
                       int* __restrict__ cntblk, int* __restrict__ flags, int r) {
  if (__hip_atomic_load(flags + r - 1, __ATOMIC_RELAXED,
                        __HIP_MEMORY_SCOPE_AGENT) == 0)
    return;                                          // converged
  __shared__ int lcnt;
  if (threadIdx.x == 0) lcnt = 0;
  int j = blockIdx.x, t = threadIdx.x;
  int n = cntblk[j];
  int b = j >> 8;                                    // 256 vertex-blocks per batch
  const int* par = parent + (b << 16);
  const ull* wk = wkey + (size_t)b * E;
  ull* mb = minE + (b << 16);
  int base = j * SEG;
  int se[3]; int ns = 0;
#pragma unroll
  for (int it = 0; it < 3; ++it) {                   // read phase (before barrier)
    int i = t + (it << 8);
    if (i < n) {
      int e = el[base + i];
      int u, v; edge_uv(e, u, v);
      int ru = find_root(par, u);
      int rv = find_root(par, v);
      if (ru != rv) {
        ull k = wk[e];
        atomicMin(mb + ru, k);                       // fire-and-forget
        atomicMin(mb + rv, k);
        se[ns++] = e;
      }
    }
  }
  __syncthreads();                                   // all reads done
  for (int i2 = 0; i2 < ns; ++i2)
    el[base + atomicAdd(&lcnt, 1)] = se[i2];         // write phase
  __syncthreads();
  if (t == 0) {
    cntblk[j] = lcnt;
    if (lcnt) {
      if (__hip_atomic_load(flags + r, __ATOMIC_RELAXED, __HIP_MEMORY_SCOPE_AGENT) == 0)
        __hip_atomic_fetch_or(flags + r, 1, __ATOMIC_RELAXED, __HIP_MEMORY_SCOPE_AGENT);
    }
  }
}

// Rounds 2..16 phase 2a: coalesced minE sweep; dirty slots (current roots)
// chase the winner edge's endpoints on STABLE parent (nobody writes parent
// here), mark the winner, and stash the hook target in hookv[].
__global__ void k_winner(const ull* __restrict__ minE, const int* __restrict__ parent,
                         int* __restrict__ hookv, float* __restrict__ out,
                         const int* __restrict__ flags, int r) {
  if (__hip_atomic_load(flags + r, __ATOMIC_RELAXED,
                        __HIP_MEMORY_SCOPE_AGENT) == 0)
    return;                                          // no merges this round
  int idx = blockIdx.x * blockDim.x + threadIdx.x;   // exact B*V grid
  ull k = minE[idx];
  if (k == ~0ULL) return;
  int b = idx >> 16, v = idx & (V - 1);
  int e = (int)(k & 0xFFFFFFFFu);
  int eu, ev; edge_uv(e, eu, ev);
  const int* par = parent + (b << 16);
  int ru = find_root(par, eu);                       // stable-parent chase
  int rv = find_root(par, ev);                       // (v is ru or rv)
  out[(size_t)b * E + e] = 1.0f;                     // winner (idempotent dup)
  hookv[idx] = (v == ru) ? rv : ru;                  // snapshot hook target
}

// Rounds 2..16 phase 2b: apply hooks (writes only; no chases -> no race),
// re-arm dirtied minE slots.
__global__ void k_apply(ull* __restrict__ minE, const int* __restrict__ hookv,
                        int* __restrict__ parent, const int* __restrict__ flags,
                        int r) {
  if (__hip_atomic_load(flags + r, __ATOMIC_RELAXED,
                        __HIP_MEMORY_SCOPE_AGENT) == 0)
    return;
  int idx = blockIdx.x * blockDim.x + threadIdx.x;   // exact B*V grid
  ull k = minE[idx];
  if (k == ~0ULL) return;
  parent[idx] = hookv[idx];
  minE[idx] = ~0ULL;                                 // re-arm
}

} // namespace

extern "C" void kernel_launch(void* const* d_in, const int* in_sizes, int n_in,
                              void* d_out, int out_size, void* d_ws, size_t ws_size,
                              hipStream_t stream) {
  const float* x = (const float*)d_in[0];
  float* out = (float*)d_out;

  char* ws = (char*)d_ws;
  size_t off = 0;
  auto alloc = [&](size_t bytes) {
    void* p = (void*)(ws + off);
    off += (bytes + 255) & ~(size_t)255;
    return p;
  };
  int* parent = (int*)alloc((size_t)B * V * sizeof(int));                      // 1 MB
  int* root   = (int*)alloc((size_t)B * V * sizeof(int));                      // 1 MB (also hookv)
  ull* minE   = (ull*)alloc((size_t)B * V * 8);                                // 2 MB
  double* n2  = (double*)alloc((size_t)B * V * sizeof(double));                // 2 MB
  ull* wkey   = (ull*)alloc((size_t)B * E * 8);                                // ~5 MB
  int* el     = (int*)alloc((size_t)NBLKV * SEG * sizeof(int));                // 3 MB
  int* cntblk = (int*)alloc((size_t)NBLKV * sizeof(int));
  int* flags  = (int*)alloc(ROUNDS * sizeof(int));

  k_norm_init<<<(B * V) / 256, 256, 0, stream>>>(x, n2, flags);
  k_weight<<<(B * E) / 256, 256, 0, stream>>>(x, n2, wkey, out);
  k_vmin0<<<(B * V) / 256, 256, 0, stream>>>(wkey, minE);
  k_hook0<<<(B * V) / 256, 256, 0, stream>>>(minE, parent, out);

  k_root <<<NBLKV, 256, 0, stream>>>(parent, root);
  k_vmin1<<<NBLKV, 256, 0, stream>>>(root, wkey, minE, flags, el, cntblk);
  k_hook1<<<NBLKV, 256, 0, stream>>>(minE, root, parent, out, flags);

  for (int r = 2; r < ROUNDS; ++r) {
    k_edge  <<<NBLKV, 256, 0, stream>>>(parent, wkey, minE, el, cntblk, flags, r);
    k_winner<<<NBLKV, 256, 0, stream>>>(minE, parent, root, out, flags, r);
    k_apply <<<NBLKV, 256, 0, stream>>>(minE, root, parent, flags, r);
  }
}